// Round 4
// baseline (300.674 us; speedup 1.0000x reference)
//
#include <hip/hip_runtime.h>
#include <hip/hip_fp16.h>
#include <math.h>

#define N_ANGLES 720
#define N_DET    725
#define N_SAMP   768
#define IMG_H    512
#define IMG_W    512

// Zero-border fp16 quad pack, shift S=4 (grid 520x520), dxy form.
// Cell (jy,jx): h[0]=(v00, v01-v00), h[1]=(v10-v00, v11-v10-v01+v00)
// bilinear = fdot2(h0 + wy2*h1, (1, wx)).  Content cells j in [3,515].
#define QW       520
#define QROWB    4160u
#define Q4BYTES  ((size_t)QW * QW * sizeof(uint2))

// zones: B1 mid-angles (banded LDS), B2 near-90 (direct), A near-axis (direct)
#define B1_ANG    358                    // a in [91,269] U [451,629]
#define B1_TILES  12                     // 12 tiles of 64 dets
#define B1N       (B1_ANG * B1_TILES)
#define B2_ANG    181                    // a in [270,450]
#define B2_DBLK   46
#define B2N       (B2_ANG * B2_DBLK)
#define AN        (181 * 3)              // a in [0,90] U [630,719]

typedef _Float16 f16x2 __attribute__((ext_vector_type(2)));

__device__ __forceinline__ f16x2 pkrtz(float a, float b) {
    auto t = __builtin_amdgcn_cvt_pkrtz(a, b);
    union { decltype(t) s; f16x2 d; } u;
    u.s = t;
    return u.d;
}

__device__ __forceinline__ float fdot2f(f16x2 a, f16x2 b, float c) {
    using hraw = decltype(__builtin_amdgcn_cvt_pkrtz(0.0f, 0.0f));
    union { f16x2 s; hraw d; } ua, ub;
    ua.s = a;
    ub.s = b;
    return __builtin_amdgcn_fdot2(ua.d, ub.d, c, false);
}

__device__ __forceinline__ float img_at(const float* __restrict__ x,
                                        const float* __restrict__ r,
                                        int py, int px) {
    if ((unsigned)py < IMG_H && (unsigned)px < IMG_W) {
        int i = py * IMG_W + px;
        return x[i] + r[i];
    }
    return 0.0f;
}

__global__ __launch_bounds__(256) void build_q8(const float* __restrict__ x,
                                                const float* __restrict__ r,
                                                uint2* __restrict__ Q,
                                                float* __restrict__ out2) {
    int t = blockIdx.x * 256 + threadIdx.x;
    if (t < (IMG_H * IMG_W / 4))
        ((float4*)out2)[t] = ((const float4*)r)[t];
    int cell = t * 4;
    if (cell >= QW * QW) return;
    int jy  = cell / QW;
    int jx0 = cell - jy * QW;
    int fy  = jy - 4;
    float row0[5], row1[5];
    #pragma unroll
    for (int e = 0; e < 5; ++e) {
        row0[e] = img_at(x, r, fy,     jx0 - 4 + e);
        row1[e] = img_at(x, r, fy + 1, jx0 - 4 + e);
    }
    uint2 o[4];
    #pragma unroll
    for (int e = 0; e < 4; ++e) {
        float A = row0[e];
        float C = row0[e + 1] - A;
        float B = row1[e] - A;
        float D = row1[e + 1] - row1[e] - C;
        union { uint2 u; __half2 h2[2]; } q;
        q.h2[0] = __floats2half2_rn(A, C);
        q.h2[1] = __floats2half2_rn(B, D);
        o[e] = q.u;
    }
    *(uint4*)(&Q[cell])     = *(uint4*)(&o[0]);
    *(uint4*)(&Q[cell + 2]) = *(uint4*)(&o[2]);
}

// direct-gather sampler for A/B2
template<int U>
__device__ __forceinline__ float run_ray(const char* __restrict__ Qb,
                                         float xs, float ys,
                                         float dx, float dy, int nb) {
    float acc = 0.0f;
    for (int k = 0; k < nb; ++k) {
        unsigned offs[U];
        float wxs[U], wys[U];
        uint2 qv[U];
        #pragma unroll
        for (int u = 0; u < U; ++u) {
            float xu = fmaf((float)u, dx, xs);
            float yu = fmaf((float)u, dy, ys);
            xu = fminf(fmaxf(xu, 0.0f), 519.0f);
            yu = fminf(fmaxf(yu, 0.0f), 519.0f);
            unsigned jx = (unsigned)xu;
            unsigned jy = (unsigned)yu;
            wxs[u] = __builtin_amdgcn_fractf(xu);
            wys[u] = __builtin_amdgcn_fractf(yu);
            offs[u] = (unsigned)__umul24(jy, QROWB) + (jx << 3);
        }
        #pragma unroll
        for (int u = 0; u < U; ++u)
            qv[u] = *(const uint2*)(Qb + offs[u]);
        #pragma unroll
        for (int u = 0; u < U; ++u) {
            union { uint2 u2; f16x2 h[2]; } q;
            q.u2 = qv[u];
            f16x2 wy2 = pkrtz(wys[u], wys[u]);
            f16x2 tb  = q.h[1] * wy2 + q.h[0];
            acc = fdot2f(tb, pkrtz(1.0f, wxs[u]), acc);
        }
        xs = fmaf((float)U, dx, xs);
        ys = fmaf((float)U, dy, ys);
    }
    return acc;
}

__device__ __forceinline__ void clip4(float X0, float Y0, float sn, float c,
                                      int& i0, int& i1) {
    float ilo = 0.0f, ihi = (float)(N_SAMP - 1);
    if (fabsf(sn) > 1e-6f) {
        float rr = -1.0f / sn;
        float a1 = (3.0f   - X0) * rr;
        float a2 = (516.0f - X0) * rr;
        ilo = fmaxf(ilo, fminf(a1, a2));
        ihi = fminf(ihi, fmaxf(a1, a2));
    } else if (X0 <= 3.0f || X0 >= 516.0f) {
        ihi = -1.0f;
    }
    if (fabsf(c) > 1e-6f) {
        float rr = 1.0f / c;
        float a1 = (3.0f   - Y0) * rr;
        float a2 = (516.0f - Y0) * rr;
        ilo = fmaxf(ilo, fminf(a1, a2));
        ihi = fminf(ihi, fmaxf(a1, a2));
    } else if (Y0 <= 3.0f || Y0 >= 516.0f) {
        ihi = -1.0f;
    }
    i0 = max(0, (int)ilo - 1);
    i1 = min(N_SAMP - 1, (int)ihi + 1);
}

__global__ __launch_bounds__(256, 8) void project_f9(const uint2* __restrict__ Q,
                                                     float* __restrict__ sino) {
    __shared__ uint2 SB[9 * 256];                 // 18432 B; 8 blocks/CU
    const char* __restrict__ Qb = (const char*)Q;
    const int bid = blockIdx.x;
    const int tid = threadIdx.x;

    if (bid < B1N) {
        // ===== B1: mid angles, row-band LDS staging ======================
        const int ang   = bid / B1_TILES;
        const int dtile = bid - ang * B1_TILES;
        const int a     = (ang < 179) ? (91 + ang) : (451 + (ang - 179));
        const int dl    = tid & 63;
        const int sl    = tid >> 6;                // sample slot = wave id
        const int dt    = dtile * 64 + dl;
        const int d     = min(dt, N_DET - 1);

        const float th = (float)((double)a * (M_PI / 720.0));
        const float c  = cosf(th);                 // |c| in [0.386, 0.922]
        const float sn = sinf(th);                 // sn  in [0.386, 0.923]
        const float s  = (float)d - 362.0f;
        const float X0 = fmaf(s, c, 259.5f) + 383.5f * sn;
        const float Y0 = fmaf(s, sn, 259.5f) - 383.5f * c;
        const float rsn = 1.0f / sn;
        const float ic  = 1.0f / c;

        // x-face clip: keep samples with x in [2, 517.5] (zero-guard-safe)
        const int ixlo = max(0,   (int)ceilf ((X0 - 517.5f) * rsn));
        const int ixhi = min(767, (int)floorf((X0 - 2.0f)   * rsn));

        // y-range of clipped samples -> band range (identical in all 4 waves)
        float ya = fmaf((float)ixlo, c, Y0);
        float yb = fmaf((float)ixhi, c, Y0);
        float ylr = fminf(ya, yb), yhr = fmaxf(ya, yb);
        if (ixlo > ixhi) { ylr = 1e9f; yhr = -1e9f; }
        #pragma unroll
        for (int m = 1; m <= 32; m <<= 1) {
            ylr = fminf(ylr, __shfl_xor(ylr, m, 64));
            yhr = fmaxf(yhr, __shfl_xor(yhr, m, 64));
        }
        int blo = 1, bhi = 0;
        if (ylr <= yhr) {
            blo = max(0,  (int)floorf(ylr * 0.125f));
            bhi = min(64, (int)floorf(yhr * 0.125f));
        }

        // scalar x-window tracker: x at (det d0+dd, y) = g(y) + dd/c
        const float t_   = sn * ic;
        const float s0   = (float)(dtile * 64) - 362.0f;
        const float X00  = fmaf(s0, c, 259.5f) + 383.5f * sn;
        const float Y00  = fmaf(s0, sn, 259.5f) - 383.5f * c;
        const float dsp  = 63.0f * ic;
        float gcur       = X00 - (8.0f * (float)blo - Y00) * t_;
        const float gstep = -8.0f * t_;

        // per-lane band-edge tracker (bitwise-shared between adjacent bands)
        float ecur      = ((float)(8 * blo) - Y0) * ic;
        const float d8  = 8.0f * ic;
        const int  kmax = ((int)(8.0f * fabsf(ic)) + 5) >> 2;
        const float sn4 = 4.0f * sn, c4 = 4.0f * c;

        float acc = 0.0f;
        for (int b = blo; b <= bhi; ++b) {
            float gn = gcur + gstep;
            float x1 = fminf(fminf(gcur, gcur + dsp), fminf(gn, gn + dsp));
            float x2 = fmaxf(fmaxf(gcur, gcur + dsp), fmaxf(gn, gn + dsp));
            gcur = gn;
            x1 = fminf(fmaxf(x1, 1.5f), 518.0f);   // bound to content region
            x2 = fminf(fmaxf(x2, 1.5f), 518.0f);
            const int xmin = (((int)floorf(x1)) - 2) & ~1;
            const int W    = min(256, ((int)ceilf(x2)) + 3 - xmin);
            const int npair = min(128, (W + 1) >> 1);

            // lane i-window for this band (exact, boundary-consistent)
            float en = ecur + d8;
            float lo = fminf(ecur, en), hi = fmaxf(ecur, en);
            ecur = en;
            const int i0 = max(ixlo, (int)ceilf(lo));
            const int i1 = min(ixhi, (int)ceilf(hi) - 1);
            const int n  = i1 - i0 + 1;

            __syncthreads();                       // prev band consumed
            // stage rows 8b..8b+8, cols xmin..xmin+W (coalesced dwordx4)
            if (W <= 128) {
                int job = tid;
                #pragma unroll
                for (int p = 0; p < 3; ++p) {      // 3*256 >= 9*64
                    int k = job >> 6, pr = job & 63;
                    if (k <= 8 && pr < npair) {
                        int py = 8 * b + k;
                        int px = xmin + 2 * pr;    // px even -> uint4 safe
                        uint4 v = make_uint4(0, 0, 0, 0);
                        if ((unsigned)py < 520u && (unsigned)px < 520u)
                            v = *(const uint4*)(Q + (py * QW + px));
                        *(uint4*)((char*)SB + (k << 11) + (pr << 4)) = v;
                    }
                    job += 256;
                }
            } else {
                int job = tid;
                #pragma unroll
                for (int p = 0; p < 5; ++p) {      // 5*256 >= 9*128
                    int k = job >> 7, pr = job & 127;
                    if (k <= 8 && pr < npair) {
                        int py = 8 * b + k;
                        int px = xmin + 2 * pr;
                        uint4 v = make_uint4(0, 0, 0, 0);
                        if ((unsigned)py < 520u && (unsigned)px < 520u)
                            v = *(const uint4*)(Q + (py * QW + px));
                        *(uint4*)((char*)SB + (k << 11) + (pr << 4)) = v;
                    }
                    job += 256;
                }
            }
            __syncthreads();                       // staging visible

            if (n > 0) {
                float xl = fmaf(-(float)(i0 + sl), sn, X0) - (float)xmin;
                float yl = fmaf( (float)(i0 + sl), c,  Y0) - (float)(8 * b);
                const float Wm1 = (float)(W - 1);
                int jj = sl;
                for (int k = 0; k < kmax; ++k) {
                    float xc = fminf(fmaxf(xl, 0.0f), Wm1);
                    float yc = fminf(fmaxf(yl, 0.0f), 8.0f);
                    int jx = (int)xc;
                    int jy = (int)yc;
                    float wx = __builtin_amdgcn_fractf(xc);
                    float wy = __builtin_amdgcn_fractf(yc);
                    union { uint2 u2; f16x2 h[2]; } q;
                    q.u2 = *(const uint2*)((char*)SB + (jy << 11) + (jx << 3));
                    f16x2 wy2 = pkrtz(wy, wy);
                    f16x2 tb  = q.h[1] * wy2 + q.h[0];
                    float a2  = fdot2f(tb, pkrtz(1.0f, wx), acc);
                    acc = (jj < n) ? a2 : acc;
                    xl -= sn4; yl += c4; jj += 4;
                }
            }
        }

        // reduce 4 sample-slots per detector
        __syncthreads();
        float* F = (float*)SB;
        F[tid] = acc;
        __syncthreads();
        if (tid < 64) {
            float r = F[tid] + F[tid + 64] + F[tid + 128] + F[tid + 192];
            int dw = dtile * 64 + tid;
            if (dw < N_DET) sino[a * N_DET + dw] = r;
        }
    } else if (bid < B1N + B2N) {
        // ===== B2: near-90, direct gather, wave = 16 t-lanes x 4 dets =====
        const int idx  = bid - B1N;
        const int a    = 270 + idx / B2_DBLK;
        const int dblk = idx % B2_DBLK;
        const int lane = tid & 63;
        const int tl   = lane & 15;
        const int grp  = lane >> 4;
        const int wv   = tid >> 6;
        const int d    = dblk * 16 + wv * 4 + grp;

        const float th = (float)((double)a * (M_PI / 720.0));
        const float c  = cosf(th);
        const float sn = sinf(th);
        const float s  = (float)d - 362.0f;
        const float X0 = fmaf(s, c, 259.5f) + 383.5f * sn;
        const float Y0 = fmaf(s, sn, 259.5f) - 383.5f * c;

        int i0, i1;
        clip4(X0, Y0, sn, c, i0, i1);
        i0 = min(i0, __shfl_xor(i0, 16, 64));
        i0 = min(i0, __shfl_xor(i0, 32, 64));
        i1 = max(i1, __shfl_xor(i1, 16, 64));
        i1 = max(i1, __shfl_xor(i1, 32, 64));
        const int trips = __builtin_amdgcn_readfirstlane((i1 - i0 + 16) >> 4);

        float xs = fmaf((float)(i0 + tl), -sn, X0);
        float ys = fmaf((float)(i0 + tl),  c,  Y0);
        float acc = run_ray<4>(Qb, xs, ys, -16.0f * sn, 16.0f * c,
                               (trips + 3) >> 2);

        acc += __shfl_xor(acc, 1, 64);
        acc += __shfl_xor(acc, 2, 64);
        acc += __shfl_xor(acc, 4, 64);
        acc += __shfl_xor(acc, 8, 64);
        if (tl == 0 && d < N_DET) sino[a * N_DET + d] = acc;
    } else {
        // ===== A: near-axis, direct gather, one thread per detector =======
        const int idx   = bid - B1N - B2N;
        const int a_idx = idx / 3;
        const int a  = (a_idx <= 90) ? a_idx : a_idx + 539;
        const int dt = (idx % 3) * 256 + tid;
        const int d  = min(dt, N_DET - 1);

        const float th = (float)((double)a * (M_PI / 720.0));
        const float c  = cosf(th);
        const float sn = sinf(th);
        const float s  = (float)d - 362.0f;
        const float X0 = fmaf(s, c, 259.5f) + 383.5f * sn;
        const float Y0 = fmaf(s, sn, 259.5f) - 383.5f * c;

        int i0, i1;
        clip4(X0, Y0, sn, c, i0, i1);
        #pragma unroll
        for (int m = 1; m <= 32; m <<= 1) {
            i0 = min(i0, __shfl_xor(i0, m, 64));
            i1 = max(i1, __shfl_xor(i1, m, 64));
        }
        const int trips = __builtin_amdgcn_readfirstlane(i1 - i0 + 1);

        float xs = fmaf((float)i0, -sn, X0);
        float ys = fmaf((float)i0,  c,  Y0);
        float acc = run_ray<8>(Qb, xs, ys, -sn, c, (trips + 7) >> 3);
        if (dt < N_DET) sino[a * N_DET + dt] = acc;
    }
}

// ---------------- launcher ---------------------------------------------------
extern "C" void kernel_launch(void* const* d_in, const int* in_sizes, int n_in,
                              void* d_out, int out_size, void* d_ws, size_t ws_size,
                              hipStream_t stream) {
    const float* x    = (const float*)d_in[0];
    const float* reco = (const float*)d_in[1];
    float* out = (float*)d_out;

    if (ws_size >= Q4BYTES) {
        uint2* Q = (uint2*)d_ws;
        build_q8<<<(QW * QW / 4 + 255) / 256, 256, 0, stream>>>(x, reco, Q,
                                                            out + N_ANGLES * N_DET);
        project_f9<<<B1N + B2N + AN, 256, 0, stream>>>(Q, out);
    }
}

// Round 5
// 205.445 us; speedup vs baseline: 1.4635x; 1.4635x over previous
//
#include <hip/hip_runtime.h>
#include <hip/hip_fp16.h>
#include <math.h>

#define N_ANGLES 720
#define N_DET    725
#define N_SAMP   768
#define IMG_H    512
#define IMG_W    512

// Zero-border fp16 quad pack, shift S=4 (grid 520x520), dxy form.
// Cell (jy,jx): h[0]=(v00, v01-v00), h[1]=(v10-v00, v11-v10-v01+v00)
// bilinear = fdot2(h0 + wy2*h1, (1, wx)).  Content cells j in [3,515].
#define QW       520
#define QROWB    4160u
#define Q4BYTES  ((size_t)QW * QW * sizeof(uint2))

// zones: A near-axis (theta<=22.5 / >=157.5), B1 mid, B2 near-90.
#define A_BLOCKS  (181 * 3)              // a in [0,90] U [630,719]
#define B1_ANG    358                    // a in [91,269] U [451,629]
#define B1G       90                     // angle groups of 4 (last clamps)
#define B1_DT     91                     // det tiles of 8
#define B1N       (B1G * B1_DT)
// B1 block = 4 consecutive angles x same 8-det tile: the 4 waves' gather
// footprints nearly coincide (<=5px spread) -> L1 serves 3 of 4 waves,
// cutting B1's L2 line traffic ~2.6x. Pure remap of the proven R1 kernel.
#define B2_ANG    181                    // a in [270,450]
#define B2_DBLK   46                     // 46 tiles of 16 detectors
#define B2N       (B2_ANG * B2_DBLK)

typedef _Float16 f16x2 __attribute__((ext_vector_type(2)));

__device__ __forceinline__ f16x2 pkrtz(float a, float b) {
    auto t = __builtin_amdgcn_cvt_pkrtz(a, b);
    union { decltype(t) s; f16x2 d; } u;
    u.s = t;
    return u.d;
}

__device__ __forceinline__ float fdot2f(f16x2 a, f16x2 b, float c) {
    using hraw = decltype(__builtin_amdgcn_cvt_pkrtz(0.0f, 0.0f));
    union { f16x2 s; hraw d; } ua, ub;
    ua.s = a;
    ub.s = b;
    return __builtin_amdgcn_fdot2(ua.d, ub.d, c, false);
}

__device__ __forceinline__ float img_at(const float* __restrict__ x,
                                        const float* __restrict__ r,
                                        int py, int px) {
    if ((unsigned)py < IMG_H && (unsigned)px < IMG_W) {
        int i = py * IMG_W + px;
        return x[i] + r[i];
    }
    return 0.0f;
}

__global__ __launch_bounds__(256) void build_q8(const float* __restrict__ x,
                                                const float* __restrict__ r,
                                                uint2* __restrict__ Q,
                                                float* __restrict__ out2) {
    int t = blockIdx.x * 256 + threadIdx.x;
    if (t < (IMG_H * IMG_W / 4))
        ((float4*)out2)[t] = ((const float4*)r)[t];
    int cell = t * 4;
    if (cell >= QW * QW) return;
    int jy  = cell / QW;
    int jx0 = cell - jy * QW;
    int fy  = jy - 4;
    float row0[5], row1[5];
    #pragma unroll
    for (int e = 0; e < 5; ++e) {
        row0[e] = img_at(x, r, fy,     jx0 - 4 + e);
        row1[e] = img_at(x, r, fy + 1, jx0 - 4 + e);
    }
    uint2 o[4];
    #pragma unroll
    for (int e = 0; e < 4; ++e) {
        float A = row0[e];
        float C = row0[e + 1] - A;
        float B = row1[e] - A;
        float D = row1[e + 1] - row1[e] - C;
        union { uint2 u; __half2 h2[2]; } q;
        q.h2[0] = __floats2half2_rn(A, C);
        q.h2[1] = __floats2half2_rn(B, D);
        o[e] = q.u;
    }
    *(uint4*)(&Q[cell])     = *(uint4*)(&o[0]);
    *(uint4*)(&Q[cell + 2]) = *(uint4*)(&o[2]);
}

// direct-gather sampler
template<int U>
__device__ __forceinline__ float run_ray(const char* __restrict__ Qb,
                                         float xs, float ys,
                                         float dx, float dy, int nb) {
    float acc = 0.0f;
    for (int k = 0; k < nb; ++k) {
        unsigned offs[U];
        float wxs[U], wys[U];
        uint2 qv[U];
        #pragma unroll
        for (int u = 0; u < U; ++u) {
            float xu = fmaf((float)u, dx, xs);
            float yu = fmaf((float)u, dy, ys);
            xu = fminf(fmaxf(xu, 0.0f), 519.0f);
            yu = fminf(fmaxf(yu, 0.0f), 519.0f);
            unsigned jx = (unsigned)xu;
            unsigned jy = (unsigned)yu;
            wxs[u] = __builtin_amdgcn_fractf(xu);
            wys[u] = __builtin_amdgcn_fractf(yu);
            offs[u] = (unsigned)__umul24(jy, QROWB) + (jx << 3);
        }
        #pragma unroll
        for (int u = 0; u < U; ++u)
            qv[u] = *(const uint2*)(Qb + offs[u]);
        #pragma unroll
        for (int u = 0; u < U; ++u) {
            union { uint2 u2; f16x2 h[2]; } q;
            q.u2 = qv[u];
            f16x2 wy2 = pkrtz(wys[u], wys[u]);
            f16x2 tb  = q.h[1] * wy2 + q.h[0];
            acc = fdot2f(tb, pkrtz(1.0f, wxs[u]), acc);
        }
        xs = fmaf((float)U, dx, xs);
        ys = fmaf((float)U, dy, ys);
    }
    return acc;
}

__device__ __forceinline__ void clip4(float X0, float Y0, float sn, float c,
                                      int& i0, int& i1) {
    float ilo = 0.0f, ihi = (float)(N_SAMP - 1);
    if (fabsf(sn) > 1e-6f) {
        float rr = -1.0f / sn;
        float a1 = (3.0f   - X0) * rr;
        float a2 = (516.0f - X0) * rr;
        ilo = fmaxf(ilo, fminf(a1, a2));
        ihi = fminf(ihi, fmaxf(a1, a2));
    } else if (X0 <= 3.0f || X0 >= 516.0f) {
        ihi = -1.0f;
    }
    if (fabsf(c) > 1e-6f) {
        float rr = 1.0f / c;
        float a1 = (3.0f   - Y0) * rr;
        float a2 = (516.0f - Y0) * rr;
        ilo = fmaxf(ilo, fminf(a1, a2));
        ihi = fminf(ihi, fmaxf(a1, a2));
    } else if (Y0 <= 3.0f || Y0 >= 516.0f) {
        ihi = -1.0f;
    }
    i0 = max(0, (int)ilo - 1);
    i1 = min(N_SAMP - 1, (int)ihi + 1);
}

__global__ __launch_bounds__(256, 8) void project_fa(const uint2* __restrict__ Q,
                                                     float* __restrict__ sino) {
    const char* __restrict__ Qb = (const char*)Q;
    const int bid = blockIdx.x;
    const int tid = threadIdx.x;

    if (bid < A_BLOCKS) {
        // ------------- A: one thread per (angle, detector), 64-det waves ----
        const int a_idx = bid / 3;
        const int a  = (a_idx <= 90) ? a_idx : a_idx + 539;  // [0,90] U [630,719]
        const int dt = (bid % 3) * 256 + tid;
        const int d  = min(dt, N_DET - 1);

        const float th = (float)((double)a * (M_PI / 720.0));
        const float c  = cosf(th);
        const float sn = sinf(th);
        const float s  = (float)d - 362.0f;
        const float X0 = fmaf(s, c, 259.5f) + 383.5f * sn;
        const float Y0 = fmaf(s, sn, 259.5f) - 383.5f * c;

        int i0, i1;
        clip4(X0, Y0, sn, c, i0, i1);
        #pragma unroll
        for (int m = 1; m <= 32; m <<= 1) {
            i0 = min(i0, __shfl_xor(i0, m, 64));
            i1 = max(i1, __shfl_xor(i1, m, 64));
        }
        const int trips = __builtin_amdgcn_readfirstlane(i1 - i0 + 1);

        float xs = fmaf((float)i0, -sn, X0);
        float ys = fmaf((float)i0,  c,  Y0);
        float acc = run_ray<8>(Qb, xs, ys, -sn, c, (trips + 7) >> 3);
        if (dt < N_DET) sino[a * N_DET + dt] = acc;
    } else if (bid < A_BLOCKS + B1N) {
        // ------------- B1: 4 angles x same 8-det tile; wave = 8d x 8t -------
        const int idx   = bid - A_BLOCKS;
        const int g     = idx / B1_DT;               // angle group
        const int dtile = idx - g * B1_DT;           // 8-det tile
        const int wv    = tid >> 6;                  // angle offset 0..3
        int ang = g * 4 + wv;
        if (ang > B1_ANG - 1) ang = B1_ANG - 1;      // dup benign (same value)
        const int a     = (ang < 179) ? (91 + ang) : (451 + (ang - 179));
        const int lane  = tid & 63;
        const int dl    = lane & 7;
        const int tl    = lane >> 3;
        const int dt    = dtile * 8 + dl;
        const int d     = min(dt, N_DET - 1);

        const float th = (float)((double)a * (M_PI / 720.0));
        const float c  = cosf(th);
        const float sn = sinf(th);
        const float s  = (float)d - 362.0f;
        const float X0 = fmaf(s, c, 259.5f) + 383.5f * sn;
        const float Y0 = fmaf(s, sn, 259.5f) - 383.5f * c;

        int i0, i1;
        clip4(X0, Y0, sn, c, i0, i1);
        #pragma unroll
        for (int m = 1; m <= 32; m <<= 1) {          // union over wave
            i0 = min(i0, __shfl_xor(i0, m, 64));
            i1 = max(i1, __shfl_xor(i1, m, 64));
        }
        const int trips = __builtin_amdgcn_readfirstlane((i1 - i0 + 8) >> 3);

        float xs = fmaf((float)(i0 + tl), -sn, X0);
        float ys = fmaf((float)(i0 + tl),  c,  Y0);
        float acc = run_ray<4>(Qb, xs, ys, -8.0f * sn, 8.0f * c,
                               (trips + 3) >> 2);

        acc += __shfl_xor(acc, 8, 64);               // reduce over tl bits
        acc += __shfl_xor(acc, 16, 64);
        acc += __shfl_xor(acc, 32, 64);
        if (tl == 0 && dt < N_DET) sino[a * N_DET + dt] = acc;
    } else {
        // ------------- B2: near-90, wave = 16 t-lanes x 4 detectors ---------
        const int idx  = bid - A_BLOCKS - B1N;
        const int a    = 270 + idx / B2_DBLK;        // [270,450]
        const int dblk = idx % B2_DBLK;
        const int lane = tid & 63;
        const int tl   = lane & 15;
        const int grp  = lane >> 4;
        const int wv   = tid >> 6;
        const int d    = dblk * 16 + wv * 4 + grp;

        const float th = (float)((double)a * (M_PI / 720.0));
        const float c  = cosf(th);
        const float sn = sinf(th);
        const float s  = (float)d - 362.0f;
        const float X0 = fmaf(s, c, 259.5f) + 383.5f * sn;
        const float Y0 = fmaf(s, sn, 259.5f) - 383.5f * c;

        int i0, i1;
        clip4(X0, Y0, sn, c, i0, i1);
        i0 = min(i0, __shfl_xor(i0, 16, 64));
        i0 = min(i0, __shfl_xor(i0, 32, 64));
        i1 = max(i1, __shfl_xor(i1, 16, 64));
        i1 = max(i1, __shfl_xor(i1, 32, 64));
        const int trips = __builtin_amdgcn_readfirstlane((i1 - i0 + 16) >> 4);

        float xs = fmaf((float)(i0 + tl), -sn, X0);
        float ys = fmaf((float)(i0 + tl),  c,  Y0);
        float acc = run_ray<4>(Qb, xs, ys, -16.0f * sn, 16.0f * c,
                               (trips + 3) >> 2);

        acc += __shfl_xor(acc, 1, 64);
        acc += __shfl_xor(acc, 2, 64);
        acc += __shfl_xor(acc, 4, 64);
        acc += __shfl_xor(acc, 8, 64);
        if (tl == 0 && d < N_DET) sino[a * N_DET + d] = acc;
    }
}

// ---------------- launcher ---------------------------------------------------
extern "C" void kernel_launch(void* const* d_in, const int* in_sizes, int n_in,
                              void* d_out, int out_size, void* d_ws, size_t ws_size,
                              hipStream_t stream) {
    const float* x    = (const float*)d_in[0];
    const float* reco = (const float*)d_in[1];
    float* out = (float*)d_out;

    if (ws_size >= Q4BYTES) {
        uint2* Q = (uint2*)d_ws;
        build_q8<<<(QW * QW / 4 + 255) / 256, 256, 0, stream>>>(x, reco, Q,
                                                            out + N_ANGLES * N_DET);
        project_fa<<<A_BLOCKS + B1N + B2N, 256, 0, stream>>>(Q, out);
    }
}

// Round 7
// 186.113 us; speedup vs baseline: 1.6155x; 1.1039x over previous
//
#include <hip/hip_runtime.h>
#include <hip/hip_fp16.h>
#include <math.h>

#define N_ANGLES 720
#define N_DET    725
#define N_SAMP   768
#define IMG_H    512
#define IMG_W    512

// 4-BYTE cells: C[jy][jx] = fp16x2 (v00, v10) = img(jy-4, jx-4), img(jy-3, jx-4).
// One 8B load at (jy,jx) spans cells jx,jx+1 -> all 4 bilinear corners:
//   L=(v00,v10), R=(v01,v11); tb = L + wx*(R-L); val = fdot2(tb, (1-wy, wy)).
// Halves the array (1.08 MB) and doubles x-coverage per 64B line vs the 8B
// quad cells -> ~25-30% fewer distinct lines per wave-gather (the limiter).
// Content cells: jx in [4,515], jy in [3,515]; outside zero. Coords clamped
// to [0,518] -> max touched byte 518*2080+518*4+8 < QW*QW*4. All overruns 0.
#define QW       520
#define QROWB    2080u                   // QW * 4 bytes per row
#define QBYTES   ((size_t)QW * QW * 4)

// zones: A near-axis (theta<=22.5 / >=157.5), B1 mid, B2 near-90.
#define A_BLOCKS  (181 * 3)              // a in [0,90] U [630,719]
#define B1_ANG    358                    // a in [91,269] U [451,629]
#define B1G       90                     // angle groups of 4
#define B1_DT     91                     // det tiles of 8
#define B1N       (B1G * B1_DT)
#define B2_ANG    181                    // a in [270,450]
#define B2_DBLK   46                     // 46 tiles of 16 detectors
#define B2N       (B2_ANG * B2_DBLK)

typedef _Float16 f16x2 __attribute__((ext_vector_type(2)));

struct Q2 { unsigned lo, hi; };          // 8B payload, align 4 (NOT uint2's 8)

__device__ __forceinline__ f16x2 pkrtz(float a, float b) {
    auto t = __builtin_amdgcn_cvt_pkrtz(a, b);
    union { decltype(t) s; f16x2 d; } u;
    u.s = t;
    return u.d;
}

__device__ __forceinline__ float fdot2f(f16x2 a, f16x2 b, float c) {
    using hraw = decltype(__builtin_amdgcn_cvt_pkrtz(0.0f, 0.0f));
    union { f16x2 s; hraw d; } ua, ub;
    ua.s = a;
    ub.s = b;
    return __builtin_amdgcn_fdot2(ua.d, ub.d, c, false);
}

__device__ __forceinline__ float img_at(const float* __restrict__ x,
                                        const float* __restrict__ r,
                                        int py, int px) {
    if ((unsigned)py < IMG_H && (unsigned)px < IMG_W) {
        int i = py * IMG_W + px;
        return x[i] + r[i];
    }
    return 0.0f;
}

// build 4B cells (8 cells/thread, 2x dwordx4 stores) + fused passthrough copy.
// GRID MUST COVER max(QW*QW/8, IMG_H*IMG_W/4) THREADS (passthrough needs 65536;
// R6's 33800-thread grid left 48% of reco uncopied -> output-1 failure).
__global__ __launch_bounds__(256) void build_q9(const float* __restrict__ x,
                                                const float* __restrict__ r,
                                                unsigned* __restrict__ Q,
                                                float* __restrict__ out2) {
    int t = blockIdx.x * 256 + threadIdx.x;
    if (t < (IMG_H * IMG_W / 4))                       // passthrough, float4
        ((float4*)out2)[t] = ((const float4*)r)[t];
    int cell = t * 8;                                  // QW%8==0: same row
    if (cell >= QW * QW) return;
    int jy  = cell / QW;
    int jx0 = cell - jy * QW;
    int fy  = jy - 4;
    unsigned o[8];
    #pragma unroll
    for (int e = 0; e < 8; ++e) {
        float v0 = img_at(x, r, fy,     jx0 - 4 + e);
        float v1 = img_at(x, r, fy + 1, jx0 - 4 + e);
        union { f16x2 h; unsigned u; } p;
        p.h = pkrtz(v0, v1);                           // (v00, v10)
        o[e] = p.u;
    }
    *(uint4*)(&Q[cell])     = *(uint4*)(&o[0]);        // cell%8==0 -> 32B align
    *(uint4*)(&Q[cell + 4]) = *(uint4*)(&o[4]);
}

// direct-gather sampler on 4B cells
template<int U>
__device__ __forceinline__ float run_ray(const char* __restrict__ Qb,
                                         float xs, float ys,
                                         float dx, float dy, int nb) {
    float acc = 0.0f;
    for (int k = 0; k < nb; ++k) {
        unsigned offs[U];
        float wxs[U], wys[U];
        Q2 qv[U];
        #pragma unroll
        for (int u = 0; u < U; ++u) {
            float xu = fmaf((float)u, dx, xs);
            float yu = fmaf((float)u, dy, ys);
            xu = fminf(fmaxf(xu, 0.0f), 518.0f);       // v_med3_f32
            yu = fminf(fmaxf(yu, 0.0f), 518.0f);
            unsigned jx = (unsigned)xu;
            unsigned jy = (unsigned)yu;
            wxs[u] = __builtin_amdgcn_fractf(xu);
            wys[u] = __builtin_amdgcn_fractf(yu);
            offs[u] = (unsigned)__umul24(jy, QROWB) + (jx << 2);
        }
        #pragma unroll
        for (int u = 0; u < U; ++u)                    // 8B load, 4B-aligned
            qv[u] = *(const Q2*)(Qb + offs[u]);
        #pragma unroll
        for (int u = 0; u < U; ++u) {
            union { unsigned w; f16x2 h; } L, R;
            L.w = qv[u].lo;                            // (v00, v10)
            R.w = qv[u].hi;                            // (v01, v11)
            f16x2 dlr = R.h - L.h;                     // v_pk_add (neg mod)
            f16x2 tb  = dlr * pkrtz(wxs[u], wxs[u]) + L.h;   // v_pk_fma
            acc = fdot2f(tb, pkrtz(1.0f - wys[u], wys[u]), acc);
        }
        xs = fmaf((float)U, dx, xs);
        ys = fmaf((float)U, dy, ys);
    }
    return acc;
}

__device__ __forceinline__ void clip4(float X0, float Y0, float sn, float c,
                                      int& i0, int& i1) {
    float ilo = 0.0f, ihi = (float)(N_SAMP - 1);
    if (fabsf(sn) > 1e-6f) {
        float rr = -1.0f / sn;
        float a1 = (3.0f   - X0) * rr;
        float a2 = (516.0f - X0) * rr;
        ilo = fmaxf(ilo, fminf(a1, a2));
        ihi = fminf(ihi, fmaxf(a1, a2));
    } else if (X0 <= 3.0f || X0 >= 516.0f) {
        ihi = -1.0f;
    }
    if (fabsf(c) > 1e-6f) {
        float rr = 1.0f / c;
        float a1 = (3.0f   - Y0) * rr;
        float a2 = (516.0f - Y0) * rr;
        ilo = fmaxf(ilo, fminf(a1, a2));
        ihi = fminf(ihi, fmaxf(a1, a2));
    } else if (Y0 <= 3.0f || Y0 >= 516.0f) {
        ihi = -1.0f;
    }
    i0 = max(0, (int)ilo - 1);
    i1 = min(N_SAMP - 1, (int)ihi + 1);
}

__global__ __launch_bounds__(256, 8) void project_fb(const unsigned* __restrict__ Q,
                                                     float* __restrict__ sino) {
    const char* __restrict__ Qb = (const char*)Q;
    const int bid = blockIdx.x;
    const int tid = threadIdx.x;

    if (bid < A_BLOCKS) {
        // ------------- A: one thread per (angle, detector), 64-det waves ----
        const int a_idx = bid / 3;
        const int a  = (a_idx <= 90) ? a_idx : a_idx + 539;  // [0,90] U [630,719]
        const int dt = (bid % 3) * 256 + tid;
        const int d  = min(dt, N_DET - 1);

        const float th = (float)((double)a * (M_PI / 720.0));
        const float c  = cosf(th);
        const float sn = sinf(th);
        const float s  = (float)d - 362.0f;
        const float X0 = fmaf(s, c, 259.5f) + 383.5f * sn;
        const float Y0 = fmaf(s, sn, 259.5f) - 383.5f * c;

        int i0, i1;
        clip4(X0, Y0, sn, c, i0, i1);
        #pragma unroll
        for (int m = 1; m <= 32; m <<= 1) {
            i0 = min(i0, __shfl_xor(i0, m, 64));
            i1 = max(i1, __shfl_xor(i1, m, 64));
        }
        const int trips = __builtin_amdgcn_readfirstlane(i1 - i0 + 1);

        float xs = fmaf((float)i0, -sn, X0);
        float ys = fmaf((float)i0,  c,  Y0);
        float acc = run_ray<8>(Qb, xs, ys, -sn, c, (trips + 7) >> 3);
        if (dt < N_DET) sino[a * N_DET + dt] = acc;
    } else if (bid < A_BLOCKS + B1N) {
        // ------------- B1: 4 angles x same 8-det tile; wave = 8d x 8t -------
        const int idx   = bid - A_BLOCKS;
        const int g     = idx / B1_DT;               // angle group
        const int dtile = idx - g * B1_DT;           // 8-det tile
        const int wv    = tid >> 6;                  // angle offset 0..3
        int ang = g * 4 + wv;
        if (ang > B1_ANG - 1) ang = B1_ANG - 1;      // dup benign (same value)
        const int a     = (ang < 179) ? (91 + ang) : (451 + (ang - 179));
        const int lane  = tid & 63;
        const int dl    = lane & 7;
        const int tl    = lane >> 3;
        const int dt    = dtile * 8 + dl;
        const int d     = min(dt, N_DET - 1);

        const float th = (float)((double)a * (M_PI / 720.0));
        const float c  = cosf(th);
        const float sn = sinf(th);
        const float s  = (float)d - 362.0f;
        const float X0 = fmaf(s, c, 259.5f) + 383.5f * sn;
        const float Y0 = fmaf(s, sn, 259.5f) - 383.5f * c;

        int i0, i1;
        clip4(X0, Y0, sn, c, i0, i1);
        #pragma unroll
        for (int m = 1; m <= 32; m <<= 1) {          // union over wave
            i0 = min(i0, __shfl_xor(i0, m, 64));
            i1 = max(i1, __shfl_xor(i1, m, 64));
        }
        const int trips = __builtin_amdgcn_readfirstlane((i1 - i0 + 8) >> 3);

        float xs = fmaf((float)(i0 + tl), -sn, X0);
        float ys = fmaf((float)(i0 + tl),  c,  Y0);
        float acc = run_ray<4>(Qb, xs, ys, -8.0f * sn, 8.0f * c,
                               (trips + 3) >> 2);

        acc += __shfl_xor(acc, 8, 64);               // reduce over tl bits
        acc += __shfl_xor(acc, 16, 64);
        acc += __shfl_xor(acc, 32, 64);
        if (tl == 0 && dt < N_DET) sino[a * N_DET + dt] = acc;
    } else {
        // ------------- B2: near-90, wave = 16 t-lanes x 4 detectors ---------
        const int idx  = bid - A_BLOCKS - B1N;
        const int a    = 270 + idx / B2_DBLK;        // [270,450]
        const int dblk = idx % B2_DBLK;
        const int lane = tid & 63;
        const int tl   = lane & 15;
        const int grp  = lane >> 4;
        const int wv   = tid >> 6;
        const int d    = dblk * 16 + wv * 4 + grp;

        const float th = (float)((double)a * (M_PI / 720.0));
        const float c  = cosf(th);
        const float sn = sinf(th);
        const float s  = (float)d - 362.0f;
        const float X0 = fmaf(s, c, 259.5f) + 383.5f * sn;
        const float Y0 = fmaf(s, sn, 259.5f) - 383.5f * c;

        int i0, i1;
        clip4(X0, Y0, sn, c, i0, i1);
        i0 = min(i0, __shfl_xor(i0, 16, 64));
        i0 = min(i0, __shfl_xor(i0, 32, 64));
        i1 = max(i1, __shfl_xor(i1, 16, 64));
        i1 = max(i1, __shfl_xor(i1, 32, 64));
        const int trips = __builtin_amdgcn_readfirstlane((i1 - i0 + 16) >> 4);

        float xs = fmaf((float)(i0 + tl), -sn, X0);
        float ys = fmaf((float)(i0 + tl),  c,  Y0);
        float acc = run_ray<4>(Qb, xs, ys, -16.0f * sn, 16.0f * c,
                               (trips + 3) >> 2);

        acc += __shfl_xor(acc, 1, 64);
        acc += __shfl_xor(acc, 2, 64);
        acc += __shfl_xor(acc, 4, 64);
        acc += __shfl_xor(acc, 8, 64);
        if (tl == 0 && d < N_DET) sino[a * N_DET + d] = acc;
    }
}

// ---------------- launcher ---------------------------------------------------
extern "C" void kernel_launch(void* const* d_in, const int* in_sizes, int n_in,
                              void* d_out, int out_size, void* d_ws, size_t ws_size,
                              hipStream_t stream) {
    const float* x    = (const float*)d_in[0];
    const float* reco = (const float*)d_in[1];
    float* out = (float*)d_out;

    if (ws_size >= QBYTES) {        // 1.08 MB; ws proven >= 2.16 MB in prior runs
        unsigned* Q = (unsigned*)d_ws;
        // grid covers BOTH jobs: passthrough (65536 threads) and cells (33800)
        const int nthreads = (IMG_H * IMG_W / 4 > QW * QW / 8)
                                 ? IMG_H * IMG_W / 4 : QW * QW / 8;
        build_q9<<<(nthreads + 255) / 256, 256, 0, stream>>>(x, reco, Q,
                                                            out + N_ANGLES * N_DET);
        project_fb<<<A_BLOCKS + B1N + B2N, 256, 0, stream>>>(Q, out);
    }
}

// Round 8
// 165.329 us; speedup vs baseline: 1.8186x; 1.1257x over previous
//
#include <hip/hip_runtime.h>
#include <hip/hip_fp16.h>
#include <math.h>

#define N_ANGLES 720
#define N_DET    725
#define N_SAMP   768
#define IMG_H    512
#define IMG_W    512

// 4-BYTE cells: C[jy][jx] = fp16x2 (v00, v10) = img(jy-4, jx-4), img(jy-3, jx-4).
// One 8B load at (jy,jx) spans cells jx,jx+1 -> all 4 bilinear corners:
//   L=(v00,v10), R=(v01,v11); tb = L + wx*(R-L); val = fdot2(tb, (1-wy, wy)).
// Content cells: jx in [4,515], jy in [3,515]; outside zero. Coords clamped
// to [0,518] -> every stray/padded sample reads zero cells -> contributes 0.
#define QW       520
#define QROWB    2080u                   // QW * 4 bytes per row
#define QBYTES   ((size_t)QW * QW * 4)

// zones: A near-axis (theta<=22.5 / >=157.5), B1 mid, B2 near-90.
// SHEAR (new this round): within a wave, lane l gets sample-index offset
// dsh(l) = -round(l * tan(theta)) along its det direction. This (a) flattens
// the wave's gather footprint onto 1-2 image rows (A) / ~8 rows (B1) --
// fewer 64B lines per wave-gather, the measured limiter -- and (b) tracks the
// per-det clip-window shift (also -tan/det), shrinking union padding.
// Any integer shear is CORRECT (padded samples clamp to zero border);
// completeness comes from unioning shear-adjusted windows.
#define A_BLOCKS  (181 * 3)              // a in [0,90] U [630,719]
#define B1_ANG    358                    // a in [91,269] U [451,629]
#define B1G       90                     // angle groups of 4
#define B1_DT     91                     // det tiles of 8
#define B1N       (B1G * B1_DT)
#define B2_ANG    181                    // a in [270,450]
#define B2_DBLK   46                     // 46 tiles of 16 detectors
#define B2N       (B2_ANG * B2_DBLK)

typedef _Float16 f16x2 __attribute__((ext_vector_type(2)));

struct Q2 { unsigned lo, hi; };          // 8B payload, align 4 (NOT uint2's 8)

__device__ __forceinline__ f16x2 pkrtz(float a, float b) {
    auto t = __builtin_amdgcn_cvt_pkrtz(a, b);
    union { decltype(t) s; f16x2 d; } u;
    u.s = t;
    return u.d;
}

__device__ __forceinline__ float fdot2f(f16x2 a, f16x2 b, float c) {
    using hraw = decltype(__builtin_amdgcn_cvt_pkrtz(0.0f, 0.0f));
    union { f16x2 s; hraw d; } ua, ub;
    ua.s = a;
    ub.s = b;
    return __builtin_amdgcn_fdot2(ua.d, ub.d, c, false);
}

__device__ __forceinline__ float img_at(const float* __restrict__ x,
                                        const float* __restrict__ r,
                                        int py, int px) {
    if ((unsigned)py < IMG_H && (unsigned)px < IMG_W) {
        int i = py * IMG_W + px;
        return x[i] + r[i];
    }
    return 0.0f;
}

// build 4B cells (8 cells/thread, 2x dwordx4 stores) + fused passthrough copy.
// GRID MUST COVER max(QW*QW/8, IMG_H*IMG_W/4) THREADS (passthrough needs 65536).
__global__ __launch_bounds__(256) void build_q9(const float* __restrict__ x,
                                                const float* __restrict__ r,
                                                unsigned* __restrict__ Q,
                                                float* __restrict__ out2) {
    int t = blockIdx.x * 256 + threadIdx.x;
    if (t < (IMG_H * IMG_W / 4))                       // passthrough, float4
        ((float4*)out2)[t] = ((const float4*)r)[t];
    int cell = t * 8;                                  // QW%8==0: same row
    if (cell >= QW * QW) return;
    int jy  = cell / QW;
    int jx0 = cell - jy * QW;
    int fy  = jy - 4;
    unsigned o[8];
    #pragma unroll
    for (int e = 0; e < 8; ++e) {
        float v0 = img_at(x, r, fy,     jx0 - 4 + e);
        float v1 = img_at(x, r, fy + 1, jx0 - 4 + e);
        union { f16x2 h; unsigned u; } p;
        p.h = pkrtz(v0, v1);                           // (v00, v10)
        o[e] = p.u;
    }
    *(uint4*)(&Q[cell])     = *(uint4*)(&o[0]);        // cell%8==0 -> 32B align
    *(uint4*)(&Q[cell + 4]) = *(uint4*)(&o[4]);
}

// direct-gather sampler on 4B cells
template<int U>
__device__ __forceinline__ float run_ray(const char* __restrict__ Qb,
                                         float xs, float ys,
                                         float dx, float dy, int nb) {
    float acc = 0.0f;
    for (int k = 0; k < nb; ++k) {
        unsigned offs[U];
        float wxs[U], wys[U];
        Q2 qv[U];
        #pragma unroll
        for (int u = 0; u < U; ++u) {
            float xu = fmaf((float)u, dx, xs);
            float yu = fmaf((float)u, dy, ys);
            xu = fminf(fmaxf(xu, 0.0f), 518.0f);       // v_med3_f32
            yu = fminf(fmaxf(yu, 0.0f), 518.0f);
            unsigned jx = (unsigned)xu;
            unsigned jy = (unsigned)yu;
            wxs[u] = __builtin_amdgcn_fractf(xu);
            wys[u] = __builtin_amdgcn_fractf(yu);
            offs[u] = (unsigned)__umul24(jy, QROWB) + (jx << 2);
        }
        #pragma unroll
        for (int u = 0; u < U; ++u)                    // 8B load, 4B-aligned
            qv[u] = *(const Q2*)(Qb + offs[u]);
        #pragma unroll
        for (int u = 0; u < U; ++u) {
            union { unsigned w; f16x2 h; } L, R;
            L.w = qv[u].lo;                            // (v00, v10)
            R.w = qv[u].hi;                            // (v01, v11)
            f16x2 dlr = R.h - L.h;                     // v_pk_add (neg mod)
            f16x2 tb  = dlr * pkrtz(wxs[u], wxs[u]) + L.h;   // v_pk_fma
            acc = fdot2f(tb, pkrtz(1.0f - wys[u], wys[u]), acc);
        }
        xs = fmaf((float)U, dx, xs);
        ys = fmaf((float)U, dy, ys);
    }
    return acc;
}

// Clip ray to content box; EMPTY lanes return a sentinel window that cannot
// win the wave union (old code returned [0,0], dragging i0 down and padding
// whole waves with wasted samples).
__device__ __forceinline__ void clip4(float X0, float Y0, float sn, float c,
                                      int& i0, int& i1) {
    float ilo = 0.0f, ihi = (float)(N_SAMP - 1);
    if (fabsf(sn) > 1e-6f) {
        float rr = -1.0f / sn;
        float a1 = (3.0f   - X0) * rr;
        float a2 = (516.0f - X0) * rr;
        ilo = fmaxf(ilo, fminf(a1, a2));
        ihi = fminf(ihi, fmaxf(a1, a2));
    } else if (X0 <= 3.0f || X0 >= 516.0f) {
        ihi = -1.0f;
    }
    if (fabsf(c) > 1e-6f) {
        float rr = 1.0f / c;
        float a1 = (3.0f   - Y0) * rr;
        float a2 = (516.0f - Y0) * rr;
        ilo = fmaxf(ilo, fminf(a1, a2));
        ihi = fminf(ihi, fmaxf(a1, a2));
    } else if (Y0 <= 3.0f || Y0 >= 516.0f) {
        ihi = -1.0f;
    }
    if (ihi < ilo) { i0 = 1 << 20; i1 = -(1 << 20); return; }  // empty
    i0 = max(0, (int)ilo - 1);
    i1 = min(N_SAMP - 1, (int)ihi + 1);
}

__global__ __launch_bounds__(256, 8) void project_fc(const unsigned* __restrict__ Q,
                                                     float* __restrict__ sino) {
    const char* __restrict__ Qb = (const char*)Q;
    const int bid = blockIdx.x;
    const int tid = threadIdx.x;

    if (bid < A_BLOCKS) {
        // ------------- A: one thread per (angle, detector), SHEARED ---------
        const int a_idx = bid / 3;
        const int a  = (a_idx <= 90) ? a_idx : a_idx + 539;  // [0,90] U [630,719]
        const int dt = (bid % 3) * 256 + tid;
        const int d  = min(dt, N_DET - 1);
        const int lane = tid & 63;

        const float th = (float)((double)a * (M_PI / 720.0));
        const float c  = cosf(th);                    // |c| >= 0.924 in A
        const float sn = sinf(th);
        const float s  = (float)d - 362.0f;
        const float X0 = fmaf(s, c, 259.5f) + 383.5f * sn;
        const float Y0 = fmaf(s, sn, 259.5f) - 383.5f * c;

        // shear: tracks the -tan(theta)/det window shift, flattens footprint
        const int dsh = -(int)rintf((float)lane * (sn / c));

        int i0, i1;
        clip4(X0, Y0, sn, c, i0, i1);
        int a0 = i0 - dsh, a1 = i1 - dsh;
        #pragma unroll
        for (int m = 1; m <= 32; m <<= 1) {
            a0 = min(a0, __shfl_xor(a0, m, 64));
            a1 = max(a1, __shfl_xor(a1, m, 64));
        }
        const int trips = __builtin_amdgcn_readfirstlane(a1 - a0 + 1);
        const int nb = (trips + 7) >> 3;              // <=0 when wave empty

        const float I0 = (float)(a0 + dsh);
        float xs = fmaf(I0, -sn, X0);
        float ys = fmaf(I0,  c,  Y0);
        float acc = run_ray<8>(Qb, xs, ys, -sn, c, nb);
        if (dt < N_DET) sino[a * N_DET + dt] = acc;
    } else if (bid < A_BLOCKS + B1N) {
        // ------------- B1: 4 angles x 8-det tile; wave = 8d x 8t, SHEARED ---
        const int idx   = bid - A_BLOCKS;
        const int g     = idx / B1_DT;               // angle group
        const int dtile = idx - g * B1_DT;           // 8-det tile
        const int wv    = tid >> 6;                  // angle offset 0..3
        int ang = g * 4 + wv;
        if (ang > B1_ANG - 1) ang = B1_ANG - 1;      // dup benign (same value)
        const int a     = (ang < 179) ? (91 + ang) : (451 + (ang - 179));
        const int lane  = tid & 63;
        const int dl    = lane & 7;
        const int tl    = lane >> 3;
        const int dt    = dtile * 8 + dl;
        const int d     = min(dt, N_DET - 1);

        const float th = (float)((double)a * (M_PI / 720.0));
        const float c  = cosf(th);                    // |c| in [0.386, 0.922]
        const float sn = sinf(th);
        const float s  = (float)d - 362.0f;
        const float X0 = fmaf(s, c, 259.5f) + 383.5f * sn;
        const float Y0 = fmaf(s, sn, 259.5f) - 383.5f * c;

        const int dsh = -(int)rintf((float)dl * (sn / c));  // |tan|<=2.42

        int i0, i1;
        clip4(X0, Y0, sn, c, i0, i1);
        int a0 = i0 - dsh, a1 = i1 - dsh;
        #pragma unroll
        for (int m = 1; m <= 32; m <<= 1) {          // union over wave
            a0 = min(a0, __shfl_xor(a0, m, 64));
            a1 = max(a1, __shfl_xor(a1, m, 64));
        }
        const int span  = __builtin_amdgcn_readfirstlane(a1 - a0 + 1);
        const int trips = (span + 8) >> 3;
        const int nb    = (trips + 3) >> 2;          // <=0 when wave empty

        const float I0 = (float)(a0 + dsh + tl);
        float xs = fmaf(I0, -sn, X0);
        float ys = fmaf(I0,  c,  Y0);
        float acc = run_ray<4>(Qb, xs, ys, -8.0f * sn, 8.0f * c, nb);

        acc += __shfl_xor(acc, 8, 64);               // reduce over tl bits
        acc += __shfl_xor(acc, 16, 64);
        acc += __shfl_xor(acc, 32, 64);
        if (tl == 0 && dt < N_DET) sino[a * N_DET + dt] = acc;
    } else {
        // ------------- B2: near-90, wave = 16 t-lanes x 4 dets (no shear) ---
        const int idx  = bid - A_BLOCKS - B1N;
        const int a    = 270 + idx / B2_DBLK;        // [270,450]
        const int dblk = idx % B2_DBLK;
        const int lane = tid & 63;
        const int tl   = lane & 15;
        const int grp  = lane >> 4;
        const int wv   = tid >> 6;
        const int d    = dblk * 16 + wv * 4 + grp;

        const float th = (float)((double)a * (M_PI / 720.0));
        const float c  = cosf(th);
        const float sn = sinf(th);
        const float s  = (float)d - 362.0f;
        const float X0 = fmaf(s, c, 259.5f) + 383.5f * sn;
        const float Y0 = fmaf(s, sn, 259.5f) - 383.5f * c;

        int i0, i1;
        clip4(X0, Y0, sn, c, i0, i1);
        i0 = min(i0, __shfl_xor(i0, 16, 64));        // union over 4 dets
        i0 = min(i0, __shfl_xor(i0, 32, 64));
        i1 = max(i1, __shfl_xor(i1, 16, 64));
        i1 = max(i1, __shfl_xor(i1, 32, 64));
        const int span  = __builtin_amdgcn_readfirstlane(i1 - i0 + 1);
        const int trips = (span + 15) >> 4;
        const int nb    = (trips + 3) >> 2;          // <=0 when wave empty

        float xs = fmaf((float)(i0 + tl), -sn, X0);
        float ys = fmaf((float)(i0 + tl),  c,  Y0);
        float acc = run_ray<4>(Qb, xs, ys, -16.0f * sn, 16.0f * c, nb);

        acc += __shfl_xor(acc, 1, 64);
        acc += __shfl_xor(acc, 2, 64);
        acc += __shfl_xor(acc, 4, 64);
        acc += __shfl_xor(acc, 8, 64);
        if (tl == 0 && d < N_DET) sino[a * N_DET + d] = acc;
    }
}

// ---------------- launcher ---------------------------------------------------
extern "C" void kernel_launch(void* const* d_in, const int* in_sizes, int n_in,
                              void* d_out, int out_size, void* d_ws, size_t ws_size,
                              hipStream_t stream) {
    const float* x    = (const float*)d_in[0];
    const float* reco = (const float*)d_in[1];
    float* out = (float*)d_out;

    if (ws_size >= QBYTES) {        // 1.08 MB; ws proven >= 2.16 MB in prior runs
        unsigned* Q = (unsigned*)d_ws;
        // grid covers BOTH jobs: passthrough (65536 threads) and cells (33800)
        const int nthreads = (IMG_H * IMG_W / 4 > QW * QW / 8)
                                 ? IMG_H * IMG_W / 4 : QW * QW / 8;
        build_q9<<<(nthreads + 255) / 256, 256, 0, stream>>>(x, reco, Q,
                                                            out + N_ANGLES * N_DET);
        project_fc<<<A_BLOCKS + B1N + B2N, 256, 0, stream>>>(Q, out);
    }
}

// Round 9
// 163.919 us; speedup vs baseline: 1.8343x; 1.0086x over previous
//
#include <hip/hip_runtime.h>
#include <hip/hip_fp16.h>
#include <math.h>

#define N_ANGLES 720
#define N_DET    725
#define N_SAMP   768
#define IMG_H    512
#define IMG_W    512

// 4-BYTE cells, VERTICAL-DELTA form: C[jy][jx] = fp16x2 (v0, dv) where
//   v0 = img(jy-4, jx-4), dv = img(jy-3, jx-4) - img(jy-4, jx-4).
// One 8B buffer load at (jy,jx) spans cells jx,jx+1 = L,R:
//   dlr = R-L; tb = L + wx*dlr = (v0(x), dv(x)); val = fdot2(tb, (1, wy)).
// Content cells: jx in [4,515], jy in [3,515]; outside zero -> any sample
// mapped to border cells contributes exactly 0 (matches reference zero-pad).
// y is UNCLAMPED: buffer num_records bounds-check returns 0 for row
// overruns (jy>=520 incl. negative-wrap; verified: u24-mul aliasing of
// negative jy lands at >=527MB offsets, always OOB). Rows 516..519 are zero
// cells. x IS clamped to [0,518] (x-wrap could alias content cells).
#define QW       520
#define QROWB    2080u                   // QW * 4 bytes per row
#define QBYTES   ((size_t)QW * QW * 4)

// zones: A near-axis (theta<=22.5 / >=157.5), B1 mid, B2 near-90.
// SHEAR (proven R8, +15%): lane l gets sample-index offset -round(l*tan)
// along det direction -> wave gather footprint flattens onto few image rows.
#define A_BLOCKS  (181 * 3)              // a in [0,90] U [630,719]
#define B1_ANG    358                    // a in [91,269] U [451,629]
#define B1G       90                     // angle groups of 4
#define B1_DT     91                     // det tiles of 8
#define B1N       (B1G * B1_DT)
#define B2_ANG    181                    // a in [270,450]
#define B2_DBLK   46                     // 46 tiles of 16 detectors
#define B2N       (B2_ANG * B2_DBLK)

typedef _Float16 f16x2 __attribute__((ext_vector_type(2)));
typedef unsigned u32x2 __attribute__((ext_vector_type(2)));
typedef unsigned u32x4 __attribute__((ext_vector_type(4)));

__device__ __forceinline__ f16x2 pkrtz(float a, float b) {
    auto t = __builtin_amdgcn_cvt_pkrtz(a, b);
    union { decltype(t) s; f16x2 d; } u;
    u.s = t;
    return u.d;
}

__device__ __forceinline__ float fdot2f(f16x2 a, f16x2 b, float c) {
    using hraw = decltype(__builtin_amdgcn_cvt_pkrtz(0.0f, 0.0f));
    union { f16x2 s; hraw d; } ua, ub;
    ua.s = a;
    ub.s = b;
    return __builtin_amdgcn_fdot2(ua.d, ub.d, c, false);
}

// SRSRC descriptor: base(48b) | stride=0 | num_records=bytes | dword raw
__device__ __forceinline__ u32x4 make_rsrc(const void* p, unsigned bytes) {
    unsigned long long a = (unsigned long long)p;
    u32x4 r;
    r.x = (unsigned)a;
    r.y = (unsigned)(a >> 32) & 0xFFFFu;
    r.z = bytes;
    r.w = 0x00020000u;
    return r;
}

__device__ __forceinline__ float img_at(const float* __restrict__ x,
                                        const float* __restrict__ r,
                                        int py, int px) {
    if ((unsigned)py < IMG_H && (unsigned)px < IMG_W) {
        int i = py * IMG_W + px;
        return x[i] + r[i];
    }
    return 0.0f;
}

// build 4B delta cells (8 cells/thread) + fused passthrough copy.
// GRID MUST COVER max(QW*QW/8, IMG_H*IMG_W/4) THREADS (passthrough = 65536).
__global__ __launch_bounds__(256) void build_qa(const float* __restrict__ x,
                                                const float* __restrict__ r,
                                                unsigned* __restrict__ Q,
                                                float* __restrict__ out2) {
    int t = blockIdx.x * 256 + threadIdx.x;
    if (t < (IMG_H * IMG_W / 4))                       // passthrough, float4
        ((float4*)out2)[t] = ((const float4*)r)[t];
    int cell = t * 8;                                  // QW%8==0: same row
    if (cell >= QW * QW) return;
    int jy  = cell / QW;
    int jx0 = cell - jy * QW;
    int fy  = jy - 4;
    unsigned o[8];
    #pragma unroll
    for (int e = 0; e < 8; ++e) {
        float v0 = img_at(x, r, fy,     jx0 - 4 + e);
        float v1 = img_at(x, r, fy + 1, jx0 - 4 + e);
        union { f16x2 h; unsigned u; } p;
        p.h = pkrtz(v0, v1 - v0);                      // (v0, dv)
        o[e] = p.u;
    }
    *(uint4*)(&Q[cell])     = *(uint4*)(&o[0]);        // cell%8==0 -> 32B align
    *(uint4*)(&Q[cell + 4]) = *(uint4*)(&o[4]);
}

// direct-gather sampler on 4B delta cells via SRSRC buffer loads.
// ~13 VALU/sample: 2 fma, 1 med3(x), 2 cvt, 2 fract, 2 addr, 1 pk_sub,
// 2 pkrtz, 1 pk_fma, 1 fdot2.  y-bound via buffer OOB (returns 0).
template<int U>
__device__ __forceinline__ float run_ray(u32x4 rsrc,
                                         float xs, float ys,
                                         float dx, float dy, int nb) {
    float acc = 0.0f;
    for (int k = 0; k < nb; ++k) {
        unsigned offs[U];
        float wxs[U], wys[U];
        u32x2 qv[U];
        #pragma unroll
        for (int u = 0; u < U; ++u) {
            float xu = fmaf((float)u, dx, xs);
            float yu = fmaf((float)u, dy, ys);
            xu = fminf(fmaxf(xu, 0.0f), 518.0f);      // v_med3_f32 (x only)
            unsigned jx = (unsigned)xu;               // defined: xu in [0,518]
            int      jy = (int)yu;                    // neg -> wrap -> OOB -> 0
            wxs[u] = __builtin_amdgcn_fractf(xu);
            wys[u] = __builtin_amdgcn_fractf(yu);
            offs[u] = (unsigned)__umul24((unsigned)jy, QROWB) + (jx << 2);
        }
        #pragma unroll
        for (int u = 0; u < U; ++u)                   // HW bounds-checked 8B
            asm volatile("buffer_load_dwordx2 %0, %1, %2, 0 offen"
                         : "=v"(qv[u]) : "v"(offs[u]), "s"(rsrc));
        asm volatile("s_waitcnt vmcnt(0)" ::: "memory");
        __builtin_amdgcn_sched_barrier(0);            // rule-18 fence
        #pragma unroll
        for (int u = 0; u < U; ++u) {
            union { unsigned w; f16x2 h; } L, R;
            L.w = qv[u].x;                            // (v0L, dvL)
            R.w = qv[u].y;                            // (v0R, dvR)
            f16x2 dlr = R.h - L.h;                    // v_pk_add (neg mod)
            f16x2 tb  = dlr * pkrtz(wxs[u], wxs[u]) + L.h;   // v_pk_fma
            acc = fdot2f(tb, pkrtz(1.0f, wys[u]), acc);      // (1, wy)
        }
        xs = fmaf((float)U, dx, xs);
        ys = fmaf((float)U, dy, ys);
    }
    return acc;
}

// Clip ray to content box; EMPTY lanes return a sentinel window that cannot
// win the wave union.
__device__ __forceinline__ void clip4(float X0, float Y0, float sn, float c,
                                      int& i0, int& i1) {
    float ilo = 0.0f, ihi = (float)(N_SAMP - 1);
    if (fabsf(sn) > 1e-6f) {
        float rr = -1.0f / sn;
        float a1 = (3.0f   - X0) * rr;
        float a2 = (516.0f - X0) * rr;
        ilo = fmaxf(ilo, fminf(a1, a2));
        ihi = fminf(ihi, fmaxf(a1, a2));
    } else if (X0 <= 3.0f || X0 >= 516.0f) {
        ihi = -1.0f;
    }
    if (fabsf(c) > 1e-6f) {
        float rr = 1.0f / c;
        float a1 = (3.0f   - Y0) * rr;
        float a2 = (516.0f - Y0) * rr;
        ilo = fmaxf(ilo, fminf(a1, a2));
        ihi = fminf(ihi, fmaxf(a1, a2));
    } else if (Y0 <= 3.0f || Y0 >= 516.0f) {
        ihi = -1.0f;
    }
    if (ihi < ilo) { i0 = 1 << 20; i1 = -(1 << 20); return; }  // empty
    i0 = max(0, (int)ilo - 1);
    i1 = min(N_SAMP - 1, (int)ihi + 1);
}

__global__ __launch_bounds__(256, 8) void project_fd(const unsigned* __restrict__ Q,
                                                     float* __restrict__ sino) {
    const u32x4 rsrc = make_rsrc(Q, (unsigned)QBYTES);
    const int bid = blockIdx.x;
    const int tid = threadIdx.x;

    if (bid < A_BLOCKS) {
        // ------------- A: one thread per (angle, detector), SHEARED ---------
        const int a_idx = bid / 3;
        const int a  = (a_idx <= 90) ? a_idx : a_idx + 539;  // [0,90] U [630,719]
        const int dt = (bid % 3) * 256 + tid;
        const int d  = min(dt, N_DET - 1);
        const int lane = tid & 63;

        const float th = (float)((double)a * (M_PI / 720.0));
        const float c  = cosf(th);                    // |c| >= 0.924 in A
        const float sn = sinf(th);
        const float s  = (float)d - 362.0f;
        const float X0 = fmaf(s, c, 259.5f) + 383.5f * sn;
        const float Y0 = fmaf(s, sn, 259.5f) - 383.5f * c;

        const int dsh = -(int)rintf((float)lane * (sn / c));

        int i0, i1;
        clip4(X0, Y0, sn, c, i0, i1);
        int a0 = i0 - dsh, a1 = i1 - dsh;
        #pragma unroll
        for (int m = 1; m <= 32; m <<= 1) {
            a0 = min(a0, __shfl_xor(a0, m, 64));
            a1 = max(a1, __shfl_xor(a1, m, 64));
        }
        const int trips = __builtin_amdgcn_readfirstlane(a1 - a0 + 1);
        const int nb = (trips + 7) >> 3;              // <=0 when wave empty

        const float I0 = (float)(a0 + dsh);
        float xs = fmaf(I0, -sn, X0);
        float ys = fmaf(I0,  c,  Y0);
        float acc = run_ray<8>(rsrc, xs, ys, -sn, c, nb);
        if (dt < N_DET) sino[a * N_DET + dt] = acc;
    } else if (bid < A_BLOCKS + B1N) {
        // ------------- B1: 4 angles x 8-det tile; wave = 8d x 8t, SHEARED ---
        const int idx   = bid - A_BLOCKS;
        const int g     = idx / B1_DT;               // angle group
        const int dtile = idx - g * B1_DT;           // 8-det tile
        const int wv    = tid >> 6;                  // angle offset 0..3
        int ang = g * 4 + wv;
        if (ang > B1_ANG - 1) ang = B1_ANG - 1;      // dup benign (same value)
        const int a     = (ang < 179) ? (91 + ang) : (451 + (ang - 179));
        const int lane  = tid & 63;
        const int dl    = lane & 7;
        const int tl    = lane >> 3;
        const int dt    = dtile * 8 + dl;
        const int d     = min(dt, N_DET - 1);

        const float th = (float)((double)a * (M_PI / 720.0));
        const float c  = cosf(th);                    // |c| in [0.386, 0.922]
        const float sn = sinf(th);
        const float s  = (float)d - 362.0f;
        const float X0 = fmaf(s, c, 259.5f) + 383.5f * sn;
        const float Y0 = fmaf(s, sn, 259.5f) - 383.5f * c;

        const int dsh = -(int)rintf((float)dl * (sn / c));  // |tan|<=2.42

        int i0, i1;
        clip4(X0, Y0, sn, c, i0, i1);
        int a0 = i0 - dsh, a1 = i1 - dsh;
        #pragma unroll
        for (int m = 1; m <= 32; m <<= 1) {          // union over wave
            a0 = min(a0, __shfl_xor(a0, m, 64));
            a1 = max(a1, __shfl_xor(a1, m, 64));
        }
        const int span  = __builtin_amdgcn_readfirstlane(a1 - a0 + 1);
        const int trips = (span + 8) >> 3;
        const int nb    = (trips + 3) >> 2;          // <=0 when wave empty

        const float I0 = (float)(a0 + dsh + tl);
        float xs = fmaf(I0, -sn, X0);
        float ys = fmaf(I0,  c,  Y0);
        float acc = run_ray<4>(rsrc, xs, ys, -8.0f * sn, 8.0f * c, nb);

        acc += __shfl_xor(acc, 8, 64);               // reduce over tl bits
        acc += __shfl_xor(acc, 16, 64);
        acc += __shfl_xor(acc, 32, 64);
        if (tl == 0 && dt < N_DET) sino[a * N_DET + dt] = acc;
    } else {
        // ------------- B2: near-90, wave = 16 t-lanes x 4 dets (no shear) ---
        const int idx  = bid - A_BLOCKS - B1N;
        const int a    = 270 + idx / B2_DBLK;        // [270,450]
        const int dblk = idx % B2_DBLK;
        const int lane = tid & 63;
        const int tl   = lane & 15;
        const int grp  = lane >> 4;
        const int wv   = tid >> 6;
        const int d    = dblk * 16 + wv * 4 + grp;

        const float th = (float)((double)a * (M_PI / 720.0));
        const float c  = cosf(th);
        const float sn = sinf(th);
        const float s  = (float)d - 362.0f;
        const float X0 = fmaf(s, c, 259.5f) + 383.5f * sn;
        const float Y0 = fmaf(s, sn, 259.5f) - 383.5f * c;

        int i0, i1;
        clip4(X0, Y0, sn, c, i0, i1);
        i0 = min(i0, __shfl_xor(i0, 16, 64));        // union over 4 dets
        i0 = min(i0, __shfl_xor(i0, 32, 64));
        i1 = max(i1, __shfl_xor(i1, 16, 64));
        i1 = max(i1, __shfl_xor(i1, 32, 64));
        const int span  = __builtin_amdgcn_readfirstlane(i1 - i0 + 1);
        const int trips = (span + 15) >> 4;
        const int nb    = (trips + 3) >> 2;          // <=0 when wave empty

        float xs = fmaf((float)(i0 + tl), -sn, X0);
        float ys = fmaf((float)(i0 + tl),  c,  Y0);
        float acc = run_ray<4>(rsrc, xs, ys, -16.0f * sn, 16.0f * c, nb);

        acc += __shfl_xor(acc, 1, 64);
        acc += __shfl_xor(acc, 2, 64);
        acc += __shfl_xor(acc, 4, 64);
        acc += __shfl_xor(acc, 8, 64);
        if (tl == 0 && d < N_DET) sino[a * N_DET + d] = acc;
    }
}

// ---------------- launcher ---------------------------------------------------
extern "C" void kernel_launch(void* const* d_in, const int* in_sizes, int n_in,
                              void* d_out, int out_size, void* d_ws, size_t ws_size,
                              hipStream_t stream) {
    const float* x    = (const float*)d_in[0];
    const float* reco = (const float*)d_in[1];
    float* out = (float*)d_out;

    if (ws_size >= QBYTES) {        // 1.08 MB; ws proven >= 2.16 MB in prior runs
        unsigned* Q = (unsigned*)d_ws;
        // grid covers BOTH jobs: passthrough (65536 threads) and cells (33800)
        const int nthreads = (IMG_H * IMG_W / 4 > QW * QW / 8)
                                 ? IMG_H * IMG_W / 4 : QW * QW / 8;
        build_qa<<<(nthreads + 255) / 256, 256, 0, stream>>>(x, reco, Q,
                                                            out + N_ANGLES * N_DET);
        project_fd<<<A_BLOCKS + B1N + B2N, 256, 0, stream>>>(Q, out);
    }
}

// Round 11
// 162.407 us; speedup vs baseline: 1.8514x; 1.0093x over previous
//
#include <hip/hip_runtime.h>
#include <hip/hip_fp16.h>
#include <math.h>

#define N_ANGLES 720
#define N_DET    725
#define N_SAMP   768
#define IMG_H    512
#define IMG_W    512

// 4-BYTE cells, VERTICAL-DELTA form: C[jy][jx] = fp16x2 (v0, dv) where
//   v0 = img(jy-4, jx-4), dv = img(jy-3, jx-4) - img(jy-4, jx-4).
// One 8B buffer load at (jy,jx) spans cells jx,jx+1 = L,R:
//   dlr = R-L; tb = L + wx*dlr = (v0(x), dv(x)); val = fdot2(tb, (1, wy)).
// Content cells: jx in [4,515], jy in [3,515]; outside zero -> any sample
// mapped to border cells contributes exactly 0 (matches reference zero-pad).
// y is UNCLAMPED: buffer num_records bounds-check returns 0 for row
// overruns (jy>=520 incl. negative-wrap; u24-mul aliasing of negative jy
// lands at >=527MB offsets, always OOB). Rows 516..519 are zero cells.
// x IS clamped to [0,518] (x-wrap could alias content cells).
#define QW       520
#define QROWB    2080u                   // QW * 4 bytes per row
#define QBYTES   ((size_t)QW * QW * 4)

// zones: A near-axis (theta<=22.5 / >=157.5), B1 mid, B2 near-90.
// SHEAR (proven R8, +15%): lane l gets sample-index offset -round(l*tan)
// along det direction -> wave gather footprint flattens onto few image rows.
#define A_BLOCKS  (181 * 3)              // a in [0,90] U [630,719]
#define B1_ANG    358                    // a in [91,269] U [451,629]
#define B1G       90                     // angle groups of 4
#define B1_DT     91                     // det tiles of 8
#define B1N       (B1G * B1_DT)
#define B2_ANG    181                    // a in [270,450]
#define B2_DBLK   46                     // 46 tiles of 16 detectors
#define B2N       (B2_ANG * B2_DBLK)

typedef _Float16 f16x2 __attribute__((ext_vector_type(2)));
typedef unsigned u32x2 __attribute__((ext_vector_type(2)));
typedef unsigned u32x4 __attribute__((ext_vector_type(4)));

// Compiler-visible buffer load: OOB-returns-0 semantics WITHOUT the
// rule-18 asm fence (R9's per-iter vmcnt(0)+sched_barrier(0) serialized
// the loop and ate the VALU savings). This ROCm's builtins take the TYPED
// __amdgpu_buffer_rsrc_t (R10 compile error with v4i32) -> use
// make_buffer_rsrc. Fallback: R9's asm path with v4i32 descriptor.
#if __has_builtin(__builtin_amdgcn_raw_buffer_load_b64) && \
    __has_builtin(__builtin_amdgcn_make_buffer_rsrc)
#define RAWBUF 1
typedef __amdgpu_buffer_rsrc_t rsrc_t;
__device__ __forceinline__ rsrc_t make_rsrc(const void* p, unsigned bytes) {
    // stride=0, num_records=bytes, word3=0x00020000 (raw dword access)
    return __builtin_amdgcn_make_buffer_rsrc(const_cast<void*>(p),
                                             (short)0, (int)bytes, 0x00020000);
}
#else
#define RAWBUF 0
typedef u32x4 rsrc_t;
__device__ __forceinline__ rsrc_t make_rsrc(const void* p, unsigned bytes) {
    unsigned long long a = (unsigned long long)p;
    u32x4 r;
    r.x = (unsigned)a;
    r.y = (unsigned)(a >> 32) & 0xFFFFu;
    r.z = bytes;
    r.w = 0x00020000u;
    return r;
}
#endif

__device__ __forceinline__ f16x2 pkrtz(float a, float b) {
    auto t = __builtin_amdgcn_cvt_pkrtz(a, b);
    union { decltype(t) s; f16x2 d; } u;
    u.s = t;
    return u.d;
}

__device__ __forceinline__ float fdot2f(f16x2 a, f16x2 b, float c) {
    using hraw = decltype(__builtin_amdgcn_cvt_pkrtz(0.0f, 0.0f));
    union { f16x2 s; hraw d; } ua, ub;
    ua.s = a;
    ub.s = b;
    return __builtin_amdgcn_fdot2(ua.d, ub.d, c, false);
}

__device__ __forceinline__ float img_at(const float* __restrict__ x,
                                        const float* __restrict__ r,
                                        int py, int px) {
    if ((unsigned)py < IMG_H && (unsigned)px < IMG_W) {
        int i = py * IMG_W + px;
        return x[i] + r[i];
    }
    return 0.0f;
}

// build 4B delta cells (8 cells/thread) + fused passthrough copy.
// GRID MUST COVER max(QW*QW/8, IMG_H*IMG_W/4) THREADS (passthrough = 65536).
__global__ __launch_bounds__(256) void build_qa(const float* __restrict__ x,
                                                const float* __restrict__ r,
                                                unsigned* __restrict__ Q,
                                                float* __restrict__ out2) {
    int t = blockIdx.x * 256 + threadIdx.x;
    if (t < (IMG_H * IMG_W / 4))                       // passthrough, float4
        ((float4*)out2)[t] = ((const float4*)r)[t];
    int cell = t * 8;                                  // QW%8==0: same row
    if (cell >= QW * QW) return;
    int jy  = cell / QW;
    int jx0 = cell - jy * QW;
    int fy  = jy - 4;
    unsigned o[8];
    #pragma unroll
    for (int e = 0; e < 8; ++e) {
        float v0 = img_at(x, r, fy,     jx0 - 4 + e);
        float v1 = img_at(x, r, fy + 1, jx0 - 4 + e);
        union { f16x2 h; unsigned u; } p;
        p.h = pkrtz(v0, v1 - v0);                      // (v0, dv)
        o[e] = p.u;
    }
    *(uint4*)(&Q[cell])     = *(uint4*)(&o[0]);        // cell%8==0 -> 32B align
    *(uint4*)(&Q[cell + 4]) = *(uint4*)(&o[4]);
}

// direct-gather sampler on 4B delta cells via SRSRC buffer loads.
// ~14 VALU/sample; y-bound via buffer OOB (returns 0).
template<int U>
__device__ __forceinline__ float run_ray(rsrc_t rsrc,
                                         float xs, float ys,
                                         float dx, float dy, int nb) {
    float acc = 0.0f;
    for (int k = 0; k < nb; ++k) {
        unsigned offs[U];
        float wxs[U], wys[U];
        u32x2 qv[U];
        #pragma unroll
        for (int u = 0; u < U; ++u) {
            float xu = fmaf((float)u, dx, xs);
            float yu = fmaf((float)u, dy, ys);
            xu = fminf(fmaxf(xu, 0.0f), 518.0f);      // v_med3_f32 (x only)
            unsigned jx = (unsigned)xu;               // defined: xu in [0,518]
            int      jy = (int)yu;                    // neg -> wrap -> OOB -> 0
            wxs[u] = __builtin_amdgcn_fractf(xu);
            wys[u] = __builtin_amdgcn_fractf(yu);
            offs[u] = (unsigned)__umul24((unsigned)jy, QROWB) + (jx << 2);
        }
#if RAWBUF
        #pragma unroll
        for (int u = 0; u < U; ++u)                   // compiler-scheduled
            qv[u] = __builtin_amdgcn_raw_buffer_load_b64(rsrc, (int)offs[u], 0, 0);
#else
        #pragma unroll
        for (int u = 0; u < U; ++u)                   // HW bounds-checked 8B
            asm volatile("buffer_load_dwordx2 %0, %1, %2, 0 offen"
                         : "=v"(qv[u]) : "v"(offs[u]), "s"(rsrc));
        asm volatile("s_waitcnt vmcnt(0)" ::: "memory");
        __builtin_amdgcn_sched_barrier(0);            // rule-18 fence
#endif
        #pragma unroll
        for (int u = 0; u < U; ++u) {
            union { unsigned w; f16x2 h; } L, R;
            L.w = qv[u].x;                            // (v0L, dvL)
            R.w = qv[u].y;                            // (v0R, dvR)
            f16x2 dlr = R.h - L.h;                    // v_pk_add (neg mod)
            f16x2 tb  = dlr * pkrtz(wxs[u], wxs[u]) + L.h;   // v_pk_fma
            acc = fdot2f(tb, pkrtz(1.0f, wys[u]), acc);      // (1, wy)
        }
        xs = fmaf((float)U, dx, xs);
        ys = fmaf((float)U, dy, ys);
    }
    return acc;
}

// Clip ray to content box; EMPTY lanes return a sentinel window that cannot
// win the wave union.
__device__ __forceinline__ void clip4(float X0, float Y0, float sn, float c,
                                      int& i0, int& i1) {
    float ilo = 0.0f, ihi = (float)(N_SAMP - 1);
    if (fabsf(sn) > 1e-6f) {
        float rr = -1.0f / sn;
        float a1 = (3.0f   - X0) * rr;
        float a2 = (516.0f - X0) * rr;
        ilo = fmaxf(ilo, fminf(a1, a2));
        ihi = fminf(ihi, fmaxf(a1, a2));
    } else if (X0 <= 3.0f || X0 >= 516.0f) {
        ihi = -1.0f;
    }
    if (fabsf(c) > 1e-6f) {
        float rr = 1.0f / c;
        float a1 = (3.0f   - Y0) * rr;
        float a2 = (516.0f - Y0) * rr;
        ilo = fmaxf(ilo, fminf(a1, a2));
        ihi = fminf(ihi, fmaxf(a1, a2));
    } else if (Y0 <= 3.0f || Y0 >= 516.0f) {
        ihi = -1.0f;
    }
    if (ihi < ilo) { i0 = 1 << 20; i1 = -(1 << 20); return; }  // empty
    i0 = max(0, (int)ilo - 1);
    i1 = min(N_SAMP - 1, (int)ihi + 1);
}

__global__ __launch_bounds__(256, 8) void project_fe(const unsigned* __restrict__ Q,
                                                     float* __restrict__ sino) {
    const rsrc_t rsrc = make_rsrc(Q, (unsigned)QBYTES);
    const int bid = blockIdx.x;
    const int tid = threadIdx.x;

    if (bid < A_BLOCKS) {
        // ------------- A: one thread per (angle, detector), SHEARED ---------
        const int a_idx = bid / 3;
        const int a  = (a_idx <= 90) ? a_idx : a_idx + 539;  // [0,90] U [630,719]
        const int dt = (bid % 3) * 256 + tid;
        const int d  = min(dt, N_DET - 1);
        const int lane = tid & 63;

        const float th = (float)((double)a * (M_PI / 720.0));
        const float c  = cosf(th);                    // |c| >= 0.924 in A
        const float sn = sinf(th);
        const float s  = (float)d - 362.0f;
        const float X0 = fmaf(s, c, 259.5f) + 383.5f * sn;
        const float Y0 = fmaf(s, sn, 259.5f) - 383.5f * c;

        const int dsh = -(int)rintf((float)lane * (sn / c));

        int i0, i1;
        clip4(X0, Y0, sn, c, i0, i1);
        int a0 = i0 - dsh, a1 = i1 - dsh;
        #pragma unroll
        for (int m = 1; m <= 32; m <<= 1) {
            a0 = min(a0, __shfl_xor(a0, m, 64));
            a1 = max(a1, __shfl_xor(a1, m, 64));
        }
        const int trips = __builtin_amdgcn_readfirstlane(a1 - a0 + 1);
        const int nb = (trips + 7) >> 3;              // <=0 when wave empty

        const float I0 = (float)(a0 + dsh);
        float xs = fmaf(I0, -sn, X0);
        float ys = fmaf(I0,  c,  Y0);
        float acc = run_ray<8>(rsrc, xs, ys, -sn, c, nb);
        if (dt < N_DET) sino[a * N_DET + dt] = acc;
    } else if (bid < A_BLOCKS + B1N) {
        // ------------- B1: 4 angles x 8-det tile; wave = 8d x 8t, SHEARED ---
        const int idx   = bid - A_BLOCKS;
        const int g     = idx / B1_DT;               // angle group
        const int dtile = idx - g * B1_DT;           // 8-det tile
        const int wv    = tid >> 6;                  // angle offset 0..3
        int ang = g * 4 + wv;
        if (ang > B1_ANG - 1) ang = B1_ANG - 1;      // dup benign (same value)
        const int a     = (ang < 179) ? (91 + ang) : (451 + (ang - 179));
        const int lane  = tid & 63;
        const int dl    = lane & 7;
        const int tl    = lane >> 3;
        const int dt    = dtile * 8 + dl;
        const int d     = min(dt, N_DET - 1);

        const float th = (float)((double)a * (M_PI / 720.0));
        const float c  = cosf(th);                    // |c| in [0.386, 0.922]
        const float sn = sinf(th);
        const float s  = (float)d - 362.0f;
        const float X0 = fmaf(s, c, 259.5f) + 383.5f * sn;
        const float Y0 = fmaf(s, sn, 259.5f) - 383.5f * c;

        const int dsh = -(int)rintf((float)dl * (sn / c));  // |tan|<=2.42

        int i0, i1;
        clip4(X0, Y0, sn, c, i0, i1);
        int a0 = i0 - dsh, a1 = i1 - dsh;
        #pragma unroll
        for (int m = 1; m <= 32; m <<= 1) {          // union over wave
            a0 = min(a0, __shfl_xor(a0, m, 64));
            a1 = max(a1, __shfl_xor(a1, m, 64));
        }
        const int span  = __builtin_amdgcn_readfirstlane(a1 - a0 + 1);
        const int trips = (span + 8) >> 3;
        const int nb    = (trips + 3) >> 2;          // <=0 when wave empty

        const float I0 = (float)(a0 + dsh + tl);
        float xs = fmaf(I0, -sn, X0);
        float ys = fmaf(I0,  c,  Y0);
        float acc = run_ray<4>(rsrc, xs, ys, -8.0f * sn, 8.0f * c, nb);

        acc += __shfl_xor(acc, 8, 64);               // reduce over tl bits
        acc += __shfl_xor(acc, 16, 64);
        acc += __shfl_xor(acc, 32, 64);
        if (tl == 0 && dt < N_DET) sino[a * N_DET + dt] = acc;
    } else {
        // ------------- B2: near-90, wave = 16 t-lanes x 4 dets (no shear) ---
        const int idx  = bid - A_BLOCKS - B1N;
        const int a    = 270 + idx / B2_DBLK;        // [270,450]
        const int dblk = idx % B2_DBLK;
        const int lane = tid & 63;
        const int tl   = lane & 15;
        const int grp  = lane >> 4;
        const int wv   = tid >> 6;
        const int d    = dblk * 16 + wv * 4 + grp;

        const float th = (float)((double)a * (M_PI / 720.0));
        const float c  = cosf(th);
        const float sn = sinf(th);
        const float s  = (float)d - 362.0f;
        const float X0 = fmaf(s, c, 259.5f) + 383.5f * sn;
        const float Y0 = fmaf(s, sn, 259.5f) - 383.5f * c;

        int i0, i1;
        clip4(X0, Y0, sn, c, i0, i1);
        i0 = min(i0, __shfl_xor(i0, 16, 64));        // union over 4 dets
        i0 = min(i0, __shfl_xor(i0, 32, 64));
        i1 = max(i1, __shfl_xor(i1, 16, 64));
        i1 = max(i1, __shfl_xor(i1, 32, 64));
        const int span  = __builtin_amdgcn_readfirstlane(i1 - i0 + 1);
        const int trips = (span + 15) >> 4;
        const int nb    = (trips + 3) >> 2;          // <=0 when wave empty

        float xs = fmaf((float)(i0 + tl), -sn, X0);
        float ys = fmaf((float)(i0 + tl),  c,  Y0);
        float acc = run_ray<4>(rsrc, xs, ys, -16.0f * sn, 16.0f * c, nb);

        acc += __shfl_xor(acc, 1, 64);
        acc += __shfl_xor(acc, 2, 64);
        acc += __shfl_xor(acc, 4, 64);
        acc += __shfl_xor(acc, 8, 64);
        if (tl == 0 && d < N_DET) sino[a * N_DET + d] = acc;
    }
}

// ---------------- launcher ---------------------------------------------------
extern "C" void kernel_launch(void* const* d_in, const int* in_sizes, int n_in,
                              void* d_out, int out_size, void* d_ws, size_t ws_size,
                              hipStream_t stream) {
    const float* x    = (const float*)d_in[0];
    const float* reco = (const float*)d_in[1];
    float* out = (float*)d_out;

    if (ws_size >= QBYTES) {        // 1.08 MB; ws proven >= 2.16 MB in prior runs
        unsigned* Q = (unsigned*)d_ws;
        // grid covers BOTH jobs: passthrough (65536 threads) and cells (33800)
        const int nthreads = (IMG_H * IMG_W / 4 > QW * QW / 8)
                                 ? IMG_H * IMG_W / 4 : QW * QW / 8;
        build_qa<<<(nthreads + 255) / 256, 256, 0, stream>>>(x, reco, Q,
                                                            out + N_ANGLES * N_DET);
        project_fe<<<A_BLOCKS + B1N + B2N, 256, 0, stream>>>(Q, out);
    }
}